// Round 1
// baseline (453.430 us; speedup 1.0000x reference)
//
#include <hip/hip_runtime.h>
#include <hip/hip_cooperative_groups.h>
#include <math.h>

namespace cg = cooperative_groups;

// Problem constants (from reference: B=8, T=4096, D=1024, fp32)
#define BB 8
#define TT 4096
#define DD 1024
#define D4 (DD / 4)      // float4s per row = 256

// Fused cooperative kernel: chunking of T
#define NCC 64           // chunks
#define CTC (TT / NCC)   // 64 rows per chunk

// Fallback 3-pass path chunking (previous verified kernel)
#define NCF 256
#define CTF (TT / NCF)   // 16

typedef float vfloat4 __attribute__((ext_vector_type(4)));

__device__ __forceinline__ float gelu_exact(float v) {
    // exact GELU: 0.5*v*(1+erf(v/sqrt(2)))
    return 0.5f * v * (1.0f + erff(v * 0.70710678118654752f));
}

__device__ __forceinline__ void gelu_acc(float4& s, const float4 v) {
    s.x += gelu_exact(v.x);
    s.y += gelu_exact(v.y);
    s.z += gelu_exact(v.z);
    s.w += gelu_exact(v.w);
}

// ---------------------------------------------------------------------------
// Fused single-kernel path (cooperative launch).
// Block (c, b) owns chunk c (64 rows) of batch b, full D width
// (256 threads x float4). All 512 blocks are co-resident
// (launch_bounds(256,2) => <=256 VGPR, 0 LDS => >=2 blocks/CU).
//
// Phase A: chunk-local masked gelu sum -> ws[b][c][d] (4 KB aggregate).
// grid.sync(): replaces the old serial k_scan kernel AND the k_partial /
//              k_apply kernel boundary.
// Phase C: exclusive chunk prefix = parallel sum of <=63 predecessor
//          aggregates (ws is 2 MB, L2/L3 resident).
// Phase D: re-read chunk rows (L3-hot: just read in phase A, x=128MiB<L3),
//          recompute gelu, running inclusive prefix, nontemporal store out.
// ---------------------------------------------------------------------------
__global__ __launch_bounds__(256, 2)
void k_fused(const float* __restrict__ x, const int* __restrict__ lengths,
             float* __restrict__ ws, float* __restrict__ out) {
    const int c  = blockIdx.x;       // chunk 0..NCC-1
    const int b  = blockIdx.y;       // batch
    const int d4 = threadIdx.x;      // 0..255 (float4 column)
    const int len = lengths[b];
    const int t0 = c * CTC;
    const int tv = min(t0 + CTC, len);   // masked-in end

    const float4* __restrict__ xp = (const float4*)(x + (size_t)b * TT * DD);

    // -------- Phase A: chunk aggregate of masked gelu --------
    float4 s = make_float4(0.f, 0.f, 0.f, 0.f);
    #pragma unroll 4
    for (int t = t0; t < tv; ++t) {
        float4 v = xp[(size_t)t * D4 + d4];
        gelu_acc(s, v);
    }
    float4* aggw = (float4*)ws + ((size_t)b * NCC + c) * D4 + d4;
    *aggw = s;

    // make aggregates visible across XCDs, then grid barrier
    __threadfence();
    cg::this_grid().sync();
    __threadfence();

    // -------- Phase C: exclusive prefix over preceding chunks --------
    float4 pre = make_float4(0.f, 0.f, 0.f, 0.f);
    const float4* aggp = (const float4*)ws + (size_t)b * NCC * D4 + d4;
    #pragma unroll 8
    for (int cc = 0; cc < c; ++cc) {
        float4 a = aggp[(size_t)cc * D4];
        pre.x += a.x; pre.y += a.y; pre.z += a.z; pre.w += a.w;
    }

    // -------- Phase D: apply (L3-warm x re-read) --------
    vfloat4* __restrict__ op = (vfloat4*)(out + (size_t)b * TT * DD);
    int t = t0;
    #pragma unroll 4
    for (; t < tv; ++t) {
        float4 v = xp[(size_t)t * D4 + d4];
        gelu_acc(pre, v);
        vfloat4 o = {v.x + pre.x, v.y + pre.y, v.z + pre.z, v.w + pre.w};
        __builtin_nontemporal_store(o, &op[(size_t)t * D4 + d4]);
    }
    // rows at/after length: plain copy (mask is 0)
    #pragma unroll 4
    for (; t < t0 + CTC; ++t) {
        float4 v = xp[(size_t)t * D4 + d4];
        vfloat4 o = {v.x, v.y, v.z, v.w};
        __builtin_nontemporal_store(o, &op[(size_t)t * D4 + d4]);
    }
}

// ---------------------------------------------------------------------------
// Fallback: previous verified 3-kernel path (used only if cooperative
// launch is rejected, e.g. unsupported under capture).
// ---------------------------------------------------------------------------
__global__ __launch_bounds__(256)
void k_partial(const float* __restrict__ x, const int* __restrict__ lengths,
               float* __restrict__ ws) {
    const int c  = blockIdx.x;
    const int b  = blockIdx.y;
    const int d4 = threadIdx.x;
    const int len = lengths[b];
    const int t0 = c * CTF;
    const int t1 = min(t0 + CTF, len);

    const float4* __restrict__ xp = (const float4*)(x + (size_t)b * TT * DD);
    float4 s = make_float4(0.f, 0.f, 0.f, 0.f);
    #pragma unroll 4
    for (int t = t0; t < t1; ++t) {
        float4 v = xp[(size_t)t * D4 + d4];
        gelu_acc(s, v);
    }
    ((float4*)ws)[((size_t)b * NCF + c) * D4 + d4] = s;
}

__global__ __launch_bounds__(256)
void k_scan(float* __restrict__ ws) {
    const int b     = blockIdx.x >> 2;
    const int dtile = blockIdx.x & 3;
    const int d     = dtile * 256 + threadIdx.x;
    float* p = ws + (size_t)b * NCF * DD + d;
    float run = 0.f;
    #pragma unroll 8
    for (int c = 0; c < NCF; ++c) {
        float v = p[(size_t)c * DD];
        p[(size_t)c * DD] = run;
        run += v;
    }
}

__global__ __launch_bounds__(256)
void k_apply(const float* __restrict__ x, const int* __restrict__ lengths,
             const float* __restrict__ ws, float* __restrict__ out) {
    const int c  = blockIdx.x;
    const int b  = blockIdx.y;
    const int d4 = threadIdx.x;
    const int len = lengths[b];
    const int t0 = c * CTF;
    const int tv = min(t0 + CTF, len);

    const float4* __restrict__ xp = (const float4*)(x + (size_t)b * TT * DD);
    vfloat4* __restrict__ op = (vfloat4*)(out + (size_t)b * TT * DD);

    float4 pre = ((const float4*)ws)[((size_t)b * NCF + c) * D4 + d4];

    int t = t0;
    #pragma unroll 4
    for (; t < tv; ++t) {
        float4 v = xp[(size_t)t * D4 + d4];
        gelu_acc(pre, v);
        vfloat4 o = {v.x + pre.x, v.y + pre.y, v.z + pre.z, v.w + pre.w};
        __builtin_nontemporal_store(o, &op[(size_t)t * D4 + d4]);
    }
    #pragma unroll 4
    for (; t < t0 + CTF; ++t) {
        float4 v = xp[(size_t)t * D4 + d4];
        vfloat4 o = {v.x, v.y, v.z, v.w};
        __builtin_nontemporal_store(o, &op[(size_t)t * D4 + d4]);
    }
}

extern "C" void kernel_launch(void* const* d_in, const int* in_sizes, int n_in,
                              void* d_out, int out_size, void* d_ws, size_t ws_size,
                              hipStream_t stream) {
    const float* x       = (const float*)d_in[0];
    const int*   lengths = (const int*)d_in[1];
    float*       out     = (float*)d_out;
    float*       ws      = (float*)d_ws;   // fused path uses 2 MB, fallback 8 MB

    dim3 blk(256, 1, 1);
    dim3 grd(NCC, BB, 1);   // 512 blocks — co-resident by construction

    void* args[] = {(void*)&x, (void*)&lengths, (void*)&ws, (void*)&out};
    hipError_t err = hipLaunchCooperativeKernel((void*)k_fused, grd, blk,
                                                args, 0, stream);
    if (err != hipSuccess) {
        // Fallback: proven 3-pass path
        dim3 g1(NCF, BB, 1);
        hipLaunchKernelGGL(k_partial, g1, blk, 0, stream, x, lengths, ws);
        dim3 g2(BB * 4, 1, 1);
        hipLaunchKernelGGL(k_scan, g2, blk, 0, stream, ws);
        hipLaunchKernelGGL(k_apply, g1, blk, 0, stream, x, lengths, ws, out);
    }
}

// Round 2
// 267.244 us; speedup vs baseline: 1.6967x; 1.6967x over previous
//
#include <hip/hip_runtime.h>
#include <math.h>

// Problem constants (from reference: B=8, T=4096, D=1024, fp32)
#define BB 8
#define TT 4096
#define DD 1024
#define NC 256           // number of T-chunks
#define CT (TT / NC)     // chunk length = 16
#define D4 (DD / 4)      // float4s per row = 256

// native clang vector type — accepted by __builtin_nontemporal_store
typedef float vfloat4 __attribute__((ext_vector_type(4)));

__device__ __forceinline__ float gelu_exact(float v) {
    // exact GELU: 0.5*v*(1+erf(v/sqrt(2)))
    return 0.5f * v * (1.0f + erff(v * 0.70710678118654752f));
}

__device__ __forceinline__ void gelu_acc(float4& s, const float4 v) {
    s.x += gelu_exact(v.x);
    s.y += gelu_exact(v.y);
    s.z += gelu_exact(v.z);
    s.w += gelu_exact(v.w);
}

// ---------------------------------------------------------------------------
// Pass 1: per-(b,chunk) masked sums of gelu(x) over the chunk's T range.
// ws layout: [B][NC][D] floats (8 MB). 2048 blocks -> full occupancy.
// Chunks fully beyond len skip the store: their aggregates are never read
// (any reader chunk c has t0_c < len, and its predecessors cc<c all have
// t0_cc < t0_c < len, i.e. all predecessors did store).
// ---------------------------------------------------------------------------
__global__ __launch_bounds__(256)
void k_partial(const float* __restrict__ x, const int* __restrict__ lengths,
               float* __restrict__ ws) {
    const int c  = blockIdx.x;       // chunk
    const int b  = blockIdx.y;       // batch
    const int d4 = threadIdx.x;      // 0..255 (float4 column)
    const int len = lengths[b];
    const int t0 = c * CT;
    if (t0 >= len) return;           // fully-masked chunk: aggregate unused
    const int t1 = min(t0 + CT, len);

    const float4* __restrict__ xp = (const float4*)(x + (size_t)b * TT * DD);
    float4 s = make_float4(0.f, 0.f, 0.f, 0.f);
    #pragma unroll 4
    for (int t = t0; t < t1; ++t) {
        float4 v = xp[(size_t)t * D4 + d4];
        gelu_acc(s, v);
    }
    ((float4*)ws)[((size_t)b * NC + c) * D4 + d4] = s;
}

// ---------------------------------------------------------------------------
// Pass 2 (fused scan+apply): each block computes its own exclusive chunk
// prefix by summing the c predecessor aggregates directly (ws is 8 MB,
// L2/L3-resident -> cheap redundant reads; replaces the old 32-block serial
// k_scan, which was latency-bound on 12% of the CUs). Then re-read the
// chunk's x rows (L3-warm), add gelu running prefix, nontemporal-store out.
// 2048 blocks, 36 VGPR, 0 LDS -> 32 waves/CU.
// ---------------------------------------------------------------------------
__global__ __launch_bounds__(256)
void k_apply(const float* __restrict__ x, const int* __restrict__ lengths,
             const float* __restrict__ ws, float* __restrict__ out) {
    const int c  = blockIdx.x;
    const int b  = blockIdx.y;
    const int d4 = threadIdx.x;
    const int len = lengths[b];
    const int t0 = c * CT;
    const int tv = min(t0 + CT, len);   // valid (masked-in) end

    const float4* __restrict__ xp = (const float4*)(x + (size_t)b * TT * DD);
    vfloat4* __restrict__ op = (vfloat4*)(out + (size_t)b * TT * DD);

    int t = t0;
    if (t0 < len) {
        // ---- exclusive prefix over preceding chunk aggregates ----
        // two accumulators break the FP dependency chain; unroll keeps
        // 8 independent 1KB/wave coalesced loads in flight.
        float4 p0 = make_float4(0.f, 0.f, 0.f, 0.f);
        float4 p1 = make_float4(0.f, 0.f, 0.f, 0.f);
        const float4* __restrict__ aggp =
            (const float4*)ws + (size_t)b * NC * D4 + d4;
        int cc = 0;
        #pragma unroll 4
        for (; cc + 1 < c; cc += 2) {
            float4 a0 = aggp[(size_t)cc * D4];
            float4 a1 = aggp[(size_t)(cc + 1) * D4];
            p0.x += a0.x; p0.y += a0.y; p0.z += a0.z; p0.w += a0.w;
            p1.x += a1.x; p1.y += a1.y; p1.z += a1.z; p1.w += a1.w;
        }
        if (cc < c) {
            float4 a0 = aggp[(size_t)cc * D4];
            p0.x += a0.x; p0.y += a0.y; p0.z += a0.z; p0.w += a0.w;
        }
        float4 pre = make_float4(p0.x + p1.x, p0.y + p1.y,
                                 p0.z + p1.z, p0.w + p1.w);

        // ---- apply: running inclusive prefix over the chunk ----
        #pragma unroll 4
        for (; t < tv; ++t) {
            float4 v = xp[(size_t)t * D4 + d4];
            gelu_acc(pre, v);
            vfloat4 o = {v.x + pre.x, v.y + pre.y, v.z + pre.z, v.w + pre.w};
            __builtin_nontemporal_store(o, &op[(size_t)t * D4 + d4]);
        }
    }
    // rows at/after length: plain copy (mask is 0)
    #pragma unroll 4
    for (; t < t0 + CT; ++t) {
        float4 v = xp[(size_t)t * D4 + d4];
        vfloat4 o = {v.x, v.y, v.z, v.w};
        __builtin_nontemporal_store(o, &op[(size_t)t * D4 + d4]);
    }
}

extern "C" void kernel_launch(void* const* d_in, const int* in_sizes, int n_in,
                              void* d_out, int out_size, void* d_ws, size_t ws_size,
                              hipStream_t stream) {
    const float* x       = (const float*)d_in[0];
    const int*   lengths = (const int*)d_in[1];
    float*       out     = (float*)d_out;
    float*       ws      = (float*)d_ws;   // needs B*NC*D*4 = 8 MB

    dim3 blk(256, 1, 1);
    dim3 g1(NC, BB, 1);
    hipLaunchKernelGGL(k_partial, g1, blk, 0, stream, x, lengths, ws);
    hipLaunchKernelGGL(k_apply,   g1, blk, 0, stream, x, lengths, ws, out);
}